// Round 14
// baseline (601.210 us; speedup 1.0000x reference)
//
#include <hip/hip_runtime.h>
#include <hip/hip_bf16.h>

#define BB 16
#define D1 1024
#define D2 1024
#define LL 512
#define TT 2048
#define LN_EPS 1e-5f

typedef unsigned short u16;
typedef __attribute__((ext_vector_type(8))) _Float16 half8;
typedef __attribute__((ext_vector_type(4))) float f32x4;
typedef __attribute__((ext_vector_type(4))) unsigned int u32x4;

__device__ __forceinline__ u16 f2h(float v) {
    _Float16 h = (_Float16)v;
    return *(u16*)&h;
}
__device__ __forceinline__ float h2f(u16 u) {
    return (float)(*(const _Float16*)&u);
}

__device__ __forceinline__ void gload_lds16(const void* g, void* l) {
    __builtin_amdgcn_global_load_lds((const __attribute__((address_space(1))) void*)g,
                                     (__attribute__((address_space(3))) void*)l, 16, 0, 0);
}

#define MEMFENCE asm volatile("" ::: "memory")
__device__ __forceinline__ void block_barrier() {
    MEMFENCE; __builtin_amdgcn_s_barrier(); MEMFENCE;
}

// ============================================================================
// BIG kernel (R12, best measured): 256x256 tile, BK=64, 512 threads (8 waves,
// 2Mx4N), double-buffered LDS, counted vmcnt(8). Projections + QK^T + PV.
// LNS=1 (with OMODE=1): accumulate LayerNorm sum/sumsq of C per batch.
// ============================================================================
template<int BIAS, int OMODE, int LNS>
__global__ __launch_bounds__(512, 2) void nt_gemm(
    const u16* __restrict__ A, const u16* __restrict__ B,
    long sAb, long sBb, long sCb,
    int N, int Kd, int gx, int gy,
    const float* __restrict__ bias,
    void* __restrict__ out0,
    const float* __restrict__ resid, long sRb,
    float* __restrict__ lnsums)
{
    __shared__ __align__(16) u16 smem[65536];

    const int nwg = gridDim.x;
    const int id = blockIdx.x;
    const int swz = (id & 7) * (nwg >> 3) + (id >> 3);
    const int bx = swz % gx;
    const int byz = swz / gx;
    const int by = byz % gy;
    const int b = byz / gy;

    const int tid = threadIdx.x;
    const long arow0 = (long)by * 256;
    const long brow0 = (long)bx * 256;
    const u16* Ab = A + (long)b * sAb + arow0 * Kd;
    const u16* Bb = B + (long)b * sBb + brow0 * Kd;

    const int wave = tid >> 6, lane = tid & 63;
    const int wm = (wave >> 2) * 128, wn = (wave & 3) * 64;
    const int lm = lane & 15, kg = lane >> 4;

    const int m0 = tid >> 3, s0 = tid & 7;
    const int nt = Kd >> 6;

    auto STAGE = [&](int buf, long k0) {
        u16* Ad = smem + buf * 32768;
        u16* Bd = smem + buf * 32768 + 16384;
#pragma unroll
        for (int call = 0; call < 4; ++call) {
            int m = call * 64 + m0;
            int gs = s0 ^ (m & 7);
            gload_lds16(Ab + k0 + (long)m * Kd + gs * 8, Ad + (call * 512 + tid) * 8);
        }
#pragma unroll
        for (int call = 0; call < 4; ++call) {
            int m = call * 64 + m0;
            int gs = s0 ^ (m & 7);
            gload_lds16(Bb + k0 + (long)m * Kd + gs * 8, Bd + (call * 512 + tid) * 8);
        }
    };

    f32x4 acc[8][4];
#pragma unroll
    for (int i = 0; i < 8; ++i)
#pragma unroll
        for (int j = 0; j < 4; ++j) acc[i][j] = (f32x4){0.f, 0.f, 0.f, 0.f};

    STAGE(0, 0);
    if (nt > 1) STAGE(1, 64);

    for (int t = 0; t < nt; ++t) {
        const int cur = t & 1;
        if (t + 1 < nt) { asm volatile("s_waitcnt vmcnt(8)" ::: "memory"); }
        else           { asm volatile("s_waitcnt vmcnt(0)" ::: "memory"); }
        block_barrier();

        const u16* Ac = smem + cur * 32768;
        const u16* Bc = smem + cur * 32768 + 16384;

        half8 bf[4][2];
#pragma unroll
        for (int f = 0; f < 4; ++f)
#pragma unroll
            for (int kf = 0; kf < 2; ++kf) {
                int nr = wn + f * 16 + lm;
                int ss = (kf * 4 + kg) ^ (nr & 7);
                bf[f][kf] = *(const half8*)(Bc + nr * 64 + ss * 8);
            }
#pragma unroll
        for (int mh = 0; mh < 2; ++mh) {
            half8 af[4][2];
#pragma unroll
            for (int f = 0; f < 4; ++f)
#pragma unroll
                for (int kf = 0; kf < 2; ++kf) {
                    int mr = wm + mh * 64 + f * 16 + lm;
                    int ss = (kf * 4 + kg) ^ (mr & 7);
                    af[f][kf] = *(const half8*)(Ac + mr * 64 + ss * 8);
                }
            __builtin_amdgcn_s_setprio(1);
#pragma unroll
            for (int f = 0; f < 4; ++f)
#pragma unroll
                for (int j = 0; j < 4; ++j)
#pragma unroll
                    for (int kf = 0; kf < 2; ++kf)
                        acc[mh * 4 + f][j] = __builtin_amdgcn_mfma_f32_16x16x32_f16(
                            af[f][kf], bf[j][kf], acc[mh * 4 + f][j], 0, 0, 0);
            __builtin_amdgcn_s_setprio(0);
        }
        block_barrier();
        if (t + 2 < nt) STAGE(cur, (long)(t + 2) * 64);
    }

    // ---- epilogue: LDS-staged (swizzled), coalesced stores; two 128-row passes ----
    float ls = 0.f, lsq = 0.f;
    float* Cs = (float*)smem;   // 128 x 256 fp32 = 128 KB
#pragma unroll
    for (int p = 0; p < 2; ++p) {
        __syncthreads();
        if (wm == p * 128) {
#pragma unroll
            for (int i = 0; i < 8; ++i)
#pragma unroll
                for (int j = 0; j < 4; ++j)
#pragma unroll
                    for (int r = 0; r < 4; ++r) {
                        int row = i * 16 + kg * 4 + r;
                        int col = wn + j * 16 + lm;
                        Cs[row * 256 + (col ^ ((row & 7) << 2))] = acc[i][j][r];
                    }
        }
        __syncthreads();
        if (OMODE == 0 || OMODE == 3) {
#pragma unroll
            for (int it = 0; it < 16; ++it) {
                int elem = it * 512 + tid;
                int row = elem >> 6, c4 = elem & 63;
                int grow = (int)arow0 + p * 128 + row;
                int gcol = (int)brow0 + c4 * 4;
                f32x4 v = *(const f32x4*)&Cs[row * 256 + ((c4 ^ (row & 7)) << 2)];
                if (BIAS == 1) v += bias[grow];
                if (BIAS == 2) v += *(const f32x4*)(bias + gcol);
                long off = (long)b * sCb + (long)grow * N + gcol;
                if (OMODE == 3) {
                    f32x4 rv = __builtin_nontemporal_load(
                        (const f32x4*)(resid + (long)b * sRb + (long)grow * N + gcol));
                    v += rv;
                    __builtin_nontemporal_store(v, (f32x4*)((float*)out0 + off));
                } else {
                    *(f32x4*)((float*)out0 + off) = v;   // reused intermediate: cached
                }
            }
        } else {
#pragma unroll
            for (int it = 0; it < 8; ++it) {
                int elem = it * 512 + tid;
                int row = elem >> 5, c8 = elem & 31;
                int grow = (int)arow0 + p * 128 + row;
                int gcol = (int)brow0 + c8 * 8;
                int g0 = (c8 * 2) ^ (row & 7);
                int g1 = (c8 * 2 + 1) ^ (row & 7);
                f32x4 u0 = *(const f32x4*)&Cs[row * 256 + g0 * 4];
                f32x4 u1 = *(const f32x4*)&Cs[row * 256 + g1 * 4];
                float vv[8] = {u0.x, u0.y, u0.z, u0.w, u1.x, u1.y, u1.z, u1.w};
                if (BIAS == 1) {
                    float bb = bias[grow];
#pragma unroll
                    for (int q = 0; q < 8; ++q) vv[q] += bb;
                }
                if (BIAS == 2) {
#pragma unroll
                    for (int q = 0; q < 8; ++q) vv[q] += bias[gcol + q];
                }
                if (LNS) {
#pragma unroll
                    for (int q = 0; q < 8; ++q) { ls += vv[q]; lsq += vv[q] * vv[q]; }
                }
                union { u16 u[8]; u32x4 v4; } pk;
#pragma unroll
                for (int q = 0; q < 8; ++q) pk.u[q] = f2h(vv[q]);
                long off = (long)b * sCb + (long)grow * N + gcol;
                *(u32x4*)((u16*)out0 + off) = pk.v4;   // reused intermediate: cached
            }
        }
    }
    if (LNS) {
#pragma unroll
        for (int off = 32; off; off >>= 1) {
            ls += __shfl_xor(ls, off, 64);
            lsq += __shfl_xor(lsq, off, 64);
        }
        __shared__ float rsum[16];
        if (lane == 0) { rsum[wave] = ls; rsum[8 + wave] = lsq; }
        __syncthreads();
        if (tid == 0) {
            float a = 0.f, c = 0.f;
#pragma unroll
            for (int w = 0; w < 8; ++w) { a += rsum[w]; c += rsum[8 + w]; }
            atomicAdd(&lnsums[b * 2], a);
            atomicAdd(&lnsums[b * 2 + 1], c);
        }
    }
}

// ============================================================================
// SMALL kernel: 128x128, BK=64, 256 thr, 32KB LDS -> 5 blocks/CU (160KB).
// For the memory-bound out-proj.
// ============================================================================
__device__ __forceinline__ void stage_tile_sm(const u16* __restrict__ g, int ldk, u16* lds, int tid) {
#pragma unroll
    for (int it = 0; it < 4; ++it) {
        int idx = it * 256 + tid;
        int m = idx >> 3, s = idx & 7;
        int gs = s ^ (m & 7);
        gload_lds16(g + (long)m * ldk + gs * 8, lds + idx * 8);
    }
}

template<int BIAS, int OMODE>
__global__ __launch_bounds__(256, 5) void nt_gemm_sm(
    const u16* __restrict__ A, const u16* __restrict__ B,
    long sAb, long sBb, long sCb,
    int N, int Kd, int gx, int gy,
    const float* __restrict__ bias,
    void* __restrict__ out0,
    const float* __restrict__ resid, long sRb)
{
    __shared__ __align__(16) u16 smem[2 * 128 * 64];
    u16* As = smem;
    u16* Bs = smem + 128 * 64;

    const int nwg = gridDim.x;
    const int id = blockIdx.x;
    const int swz = (id & 7) * (nwg >> 3) + (id >> 3);
    const int bx = swz % gx;
    const int byz = swz / gx;
    const int by = byz % gy;
    const int b = byz / gy;

    const int tid = threadIdx.x;
    const long arow0 = (long)by * 128;
    const long brow0 = (long)bx * 128;
    const u16* Ab = A + (long)b * sAb + arow0 * Kd;
    const u16* Bb = B + (long)b * sBb + brow0 * Kd;

    const int wave = tid >> 6, lane = tid & 63;
    const int wm = (wave >> 1) * 64, wn = (wave & 1) * 64;
    const int lm = lane & 15, kg = lane >> 4;

    f32x4 acc[4][4];
#pragma unroll
    for (int i = 0; i < 4; ++i)
#pragma unroll
        for (int j = 0; j < 4; ++j) acc[i][j] = (f32x4){0.f, 0.f, 0.f, 0.f};

    for (int k0 = 0; k0 < Kd; k0 += 64) {
        stage_tile_sm(Ab + k0, Kd, As, tid);
        stage_tile_sm(Bb + k0, Kd, Bs, tid);
        __syncthreads();
#pragma unroll
        for (int ks = 0; ks < 2; ++ks) {
            half8 af[4], bf[4];
#pragma unroll
            for (int f = 0; f < 4; ++f) {
                int mr = wm + f * 16 + lm;
                int as_ = (ks * 4 + kg) ^ (mr & 7);
                af[f] = *(const half8*)(As + mr * 64 + as_ * 8);
                int nr = wn + f * 16 + lm;
                int bs_ = (ks * 4 + kg) ^ (nr & 7);
                bf[f] = *(const half8*)(Bs + nr * 64 + bs_ * 8);
            }
#pragma unroll
            for (int i = 0; i < 4; ++i)
#pragma unroll
                for (int j = 0; j < 4; ++j)
                    acc[i][j] = __builtin_amdgcn_mfma_f32_16x16x32_f16(af[i], bf[j], acc[i][j], 0, 0, 0);
        }
        __syncthreads();
    }

    float* Cs = (float*)smem;
#pragma unroll
    for (int p = 0; p < 2; ++p) {
        if (p) __syncthreads();
        if (wm == p * 64) {
#pragma unroll
            for (int i = 0; i < 4; ++i)
#pragma unroll
                for (int j = 0; j < 4; ++j)
#pragma unroll
                    for (int r = 0; r < 4; ++r) {
                        int row = i * 16 + kg * 4 + r;
                        int col = wn + j * 16 + lm;
                        Cs[row * 128 + (col ^ ((row & 7) << 2))] = acc[i][j][r];
                    }
        }
        __syncthreads();
        if (OMODE == 0 || OMODE == 3) {
#pragma unroll
            for (int rr = 0; rr < 8; ++rr) {
                int elem = rr * 256 + tid;
                int row = elem >> 5, c4 = elem & 31;
                int grow = (int)arow0 + p * 64 + row;
                int gcol = (int)brow0 + c4 * 4;
                f32x4 v = *(const f32x4*)&Cs[row * 128 + ((c4 ^ (row & 7)) << 2)];
                if (BIAS == 1) v += bias[grow];
                if (BIAS == 2) v += *(const f32x4*)(bias + gcol);
                long off = (long)b * sCb + (long)grow * N + gcol;
                if (OMODE == 3) {
                    f32x4 rv = __builtin_nontemporal_load(
                        (const f32x4*)(resid + (long)b * sRb + (long)grow * N + gcol));
                    v += rv;
                    __builtin_nontemporal_store(v, (f32x4*)((float*)out0 + off));
                } else {
                    *(f32x4*)((float*)out0 + off) = v;
                }
            }
        } else {
#pragma unroll
            for (int rr = 0; rr < 4; ++rr) {
                int elem = rr * 256 + tid;
                int row = elem >> 4, c8 = elem & 15;
                int grow = (int)arow0 + p * 64 + row;
                int gcol = (int)brow0 + c8 * 8;
                int g0 = (c8 * 2) ^ (row & 7);
                int g1 = (c8 * 2 + 1) ^ (row & 7);
                f32x4 u0 = *(const f32x4*)&Cs[row * 128 + g0 * 4];
                f32x4 u1 = *(const f32x4*)&Cs[row * 128 + g1 * 4];
                float vv[8] = {u0.x, u0.y, u0.z, u0.w, u1.x, u1.y, u1.z, u1.w};
                if (BIAS == 1) {
                    float bb = bias[grow];
#pragma unroll
                    for (int q = 0; q < 8; ++q) vv[q] += bb;
                }
                if (BIAS == 2) {
#pragma unroll
                    for (int q = 0; q < 8; ++q) vv[q] += bias[gcol + q];
                }
                union { u16 u[8]; u32x4 v4; } pk;
#pragma unroll
                for (int q = 0; q < 8; ++q) pk.u[q] = f2h(vv[q]);
                long off = (long)b * sCb + (long)grow * N + gcol;
                *(u32x4*)((u16*)out0 + off) = pk.v4;
            }
        }
    }
}

// fp32 [D][T] (per batch) -> fp16 [T][D], vectorized 16B/lane writes
__global__ __launch_bounds__(256) void transpose_h(const float* __restrict__ in,
                                                   u16* __restrict__ o16, int D, int T) {
    __shared__ float tile[64][65];
    int b = blockIdx.z;
    const float* src = in + (long)b * D * T;
    long obase = (long)b * D * T;
    int t0 = blockIdx.x * 64, d0 = blockIdx.y * 64;
    int tx = threadIdx.x & 63, ty = threadIdx.x >> 6;
#pragma unroll
    for (int i = 0; i < 64; i += 4)
        tile[ty + i][tx] = __builtin_nontemporal_load(&src[(long)(d0 + ty + i) * T + t0 + tx]);
    __syncthreads();
    // each item = one t-row x 8 consecutive d -> one 16B store (full lines per 8 lanes)
#pragma unroll
    for (int it = 0; it < 2; ++it) {
        int item = it * 256 + threadIdx.x;   // 0..511
        int tl = item >> 3, dc = item & 7;
        union { u16 u[8]; u32x4 v4; } pk;
#pragma unroll
        for (int q = 0; q < 8; ++q) pk.u[q] = f2h(tile[dc * 8 + q][tl]);
        *(u32x4*)(o16 + obase + (long)(t0 + tl) * D + d0 + dc * 8) = pk.v4;
    }
}

// fp32 [R][C] -> fp32 [C][R]
__global__ __launch_bounds__(256) void transpose_f32(const float* __restrict__ in,
                                                     float* __restrict__ out, int R, int C) {
    __shared__ float tile[64][65];
    int c0 = blockIdx.x * 64, r0 = blockIdx.y * 64;
    int tx = threadIdx.x & 63, ty = threadIdx.x >> 6;
#pragma unroll
    for (int i = 0; i < 64; i += 4)
        tile[ty + i][tx] = in[(long)(r0 + ty + i) * C + c0 + tx];
    __syncthreads();
#pragma unroll
    for (int i = 0; i < 64; i += 4)
        out[(long)(c0 + ty + i) * R + r0 + tx] = tile[tx][ty + i];
}

__global__ __launch_bounds__(256) void conv_w(const float* __restrict__ w,
                                              u16* __restrict__ h, int n) {
    int i = blockIdx.x * 256 + threadIdx.x;
    if (i < n) h[i] = f2h(w[i]);
}

// one block per score row (2048 cols), fp32 in (L3-resident), fp16 prob out
__global__ __launch_bounds__(256) void softmax_rows(const float* __restrict__ S, u16* __restrict__ P) {
    long row = (long)blockIdx.z * TT + blockIdx.x;
    const float* s = S + row * TT;
    u16* p = P + row * TT;
    int tid = threadIdx.x;
    f32x4 v0 = *(const f32x4*)(s + tid * 8);
    f32x4 v1 = *(const f32x4*)(s + tid * 8 + 4);
    float x[8] = {v0.x, v0.y, v0.z, v0.w, v1.x, v1.y, v1.z, v1.w};
    float m = x[0];
#pragma unroll
    for (int j = 1; j < 8; ++j) m = fmaxf(m, x[j]);
#pragma unroll
    for (int off = 32; off; off >>= 1) m = fmaxf(m, __shfl_xor(m, off, 64));
    __shared__ float red[8];
    int wave = tid >> 6, lane = tid & 63;
    if (lane == 0) red[wave] = m;
    __syncthreads();
    m = fmaxf(fmaxf(red[0], red[1]), fmaxf(red[2], red[3]));
    float e[8]; float sum = 0.f;
#pragma unroll
    for (int j = 0; j < 8; ++j) { e[j] = __expf(x[j] - m); sum += e[j]; }
#pragma unroll
    for (int off = 32; off; off >>= 1) sum += __shfl_xor(sum, off, 64);
    if (lane == 0) red[4 + wave] = sum;
    __syncthreads();
    sum = red[4] + red[5] + red[6] + red[7];
    float inv = 1.f / sum;
    union { u16 u[8]; u32x4 v4; } pk;
#pragma unroll
    for (int j = 0; j < 8; ++j) pk.u[j] = f2h(e[j] * inv);
    *(u32x4*)(p + tid * 8) = pk.v4;
}

__global__ void zero32(float* p) { p[threadIdx.x] = 0.f; }

__global__ __launch_bounds__(256) void ln_apply(const u16* __restrict__ TXp, const float* __restrict__ sums,
                                                const float* __restrict__ gT, const float* __restrict__ bT,
                                                u16* __restrict__ H) {
    int b = blockIdx.z;
    const float n = (float)(LL * TT);
    float mu = sums[b * 2] / n;
    float var = sums[b * 2 + 1] / n - mu * mu;
    float rstd = rsqrtf(var + LN_EPS);
    long base = (long)b * (LL * TT);
    long idx = ((long)blockIdx.x * 256 + threadIdx.x) * 8;
    u32x4 xv = *(const u32x4*)(TXp + base + idx);
    unsigned w[4] = {xv.x, xv.y, xv.z, xv.w};
    f32x4 g0 = *(const f32x4*)(gT + idx);
    f32x4 g1 = *(const f32x4*)(gT + idx + 4);
    f32x4 b0 = *(const f32x4*)(bT + idx);
    f32x4 b1 = *(const f32x4*)(bT + idx + 4);
    float g[8] = {g0.x, g0.y, g0.z, g0.w, g1.x, g1.y, g1.z, g1.w};
    float be[8] = {b0.x, b0.y, b0.z, b0.w, b1.x, b1.y, b1.z, b1.w};
    union { u16 u[8]; u32x4 v; } pk;
#pragma unroll
    for (int q = 0; q < 4; ++q) {
        float a = h2f((u16)(w[q] & 0xffff));
        float c = h2f((u16)(w[q] >> 16));
        float oa = fmaxf((a - mu) * rstd * g[q * 2] + be[q * 2], 0.f);
        float oc = fmaxf((c - mu) * rstd * g[q * 2 + 1] + be[q * 2 + 1], 0.f);
        pk.u[q * 2] = f2h(oa);
        pk.u[q * 2 + 1] = f2h(oc);
    }
    *(u32x4*)(H + base + idx) = pk.v;
}

extern "C" void kernel_launch(void* const* d_in, const int* in_sizes, int n_in,
                              void* d_out, int out_size, void* d_ws, size_t ws_size,
                              hipStream_t stream) {
    const float* input1  = (const float*)d_in[0];
    const float* input2  = (const float*)d_in[1];
    const float* theta_w = (const float*)d_in[2];
    const float* theta_b = (const float*)d_in[3];
    const float* phi_w   = (const float*)d_in[4];
    const float* phi_b   = (const float*)d_in[5];
    const float* g_w     = (const float*)d_in[6];
    const float* g_b     = (const float*)d_in[7];
    const float* ln_gamma= (const float*)d_in[8];
    const float* ln_beta = (const float*)d_in[9];
    const float* out_w   = (const float*)d_in[10];
    const float* out_b   = (const float*)d_in[11];
    float* out = (float*)d_out;

    char* ws = (char*)d_ws;
    const size_t MB = 1ull << 20;
    u16*  Xt     = (u16*)(ws + 0);          // 64MB [B][T][1024] fp16 (dead after projections)
    float* scores= (float*)(ws + 0);        // 64MB [4][T][T] fp32 (reuses Xt region, L3-resident)
    u16*  pmat   = (u16*)(ws + 64 * MB);    // 128MB [16][T][T] fp16
    u16*  Qf     = (u16*)(ws + 192 * MB);   // 32MB [B][T][L]
    u16*  Kf     = (u16*)(ws + 224 * MB);   // 32MB [B][T][L]
    u16*  Vt     = (u16*)(ws + 256 * MB);   // 32MB [B][L][T]
    u16*  TX     = (u16*)(ws + 288 * MB);   // 32MB [B][T][L] fp16
    u16*  H      = (u16*)(ws + 320 * MB);   // 32MB [B][T][L]
    u16*  thw    = (u16*)(ws + 352 * MB);   // 1MB each
    u16*  phw    = (u16*)(ws + 353 * MB);
    u16*  gww    = (u16*)(ws + 354 * MB);
    u16*  oww    = (u16*)(ws + 355 * MB);
    float* gammaT= (float*)(ws + 356 * MB); // 4MB [T][L]
    float* betaT = (float*)(ws + 360 * MB); // 4MB
    float* sums  = (float*)(ws + 364 * MB); // 128B

    dim3 blk(256), blk5(512);

    conv_w<<<dim3((LL * D2 + 255) / 256), blk, 0, stream>>>(theta_w, thw, LL * D2);
    conv_w<<<dim3((LL * D1 + 255) / 256), blk, 0, stream>>>(phi_w, phw, LL * D1);
    conv_w<<<dim3((LL * D1 + 255) / 256), blk, 0, stream>>>(g_w, gww, LL * D1);
    conv_w<<<dim3((D2 * LL + 255) / 256), blk, 0, stream>>>(out_w, oww, D2 * LL);
    transpose_f32<<<dim3(TT / 64, LL / 64, 1), blk, 0, stream>>>(ln_gamma, gammaT, LL, TT);
    transpose_f32<<<dim3(TT / 64, LL / 64, 1), blk, 0, stream>>>(ln_beta, betaT, LL, TT);
    zero32<<<dim3(1), dim3(32), 0, stream>>>(sums);

    // Q = theta(input2)
    transpose_h<<<dim3(TT / 64, D2 / 64, BB), blk, 0, stream>>>(input2, Xt, D2, TT);
    nt_gemm<2, 1, 0><<<dim3((LL / 256) * (TT / 256) * BB), blk5, 0, stream>>>(
        Xt, thw, (long)TT * D2, 0, (long)TT * LL, LL, D2, LL / 256, TT / 256,
        theta_b, Qf, nullptr, 0, nullptr);

    // K = phi(input1), V^T = g(input1)
    transpose_h<<<dim3(TT / 64, D1 / 64, BB), blk, 0, stream>>>(input1, Xt, D1, TT);
    nt_gemm<2, 1, 0><<<dim3((LL / 256) * (TT / 256) * BB), blk5, 0, stream>>>(
        Xt, phw, (long)TT * D1, 0, (long)TT * LL, LL, D1, LL / 256, TT / 256,
        phi_b, Kf, nullptr, 0, nullptr);
    nt_gemm<1, 1, 0><<<dim3((TT / 256) * (LL / 256) * BB), blk5, 0, stream>>>(
        gww, Xt, 0, (long)TT * D1, (long)LL * TT, TT, D1, TT / 256, LL / 256,
        g_b, Vt, nullptr, 0, nullptr);

    // attention scores+softmax, 4 batches per chunk (scores reuse Xt region)
    for (int c = 0; c < 4; ++c) {
        long qoff = (long)c * 4 * TT * LL;
        nt_gemm<0, 0, 0><<<dim3((TT / 256) * (TT / 256) * 4), blk5, 0, stream>>>(
            Qf + qoff, Kf + qoff, (long)TT * LL, (long)TT * LL, (long)TT * TT,
            TT, LL, TT / 256, TT / 256, nullptr, scores, nullptr, 0, nullptr);
        softmax_rows<<<dim3(TT, 1, 4), blk, 0, stream>>>(scores, pmat + (long)c * 4 * TT * TT);
    }
    // PV: one full-GPU dispatch over all 16 batches, LayerNorm sums fused
    nt_gemm<0, 1, 1><<<dim3((LL / 256) * (TT / 256) * BB), blk5, 0, stream>>>(
        pmat, Vt, (long)TT * TT, (long)LL * TT, (long)TT * LL,
        LL, TT, LL / 256, TT / 256, nullptr, TX, nullptr, 0, sums);

    ln_apply<<<dim3(512, 1, BB), blk, 0, stream>>>(TX, sums, gammaT, betaT, H);

    // out = out_w * h + out_b + input2  (small kernel, 5 blocks/CU)
    nt_gemm_sm<1, 3><<<dim3((TT / 128) * (D2 / 128) * BB), blk, 0, stream>>>(
        oww, H, 0, (long)TT * LL, (long)D2 * TT, TT, LL, TT / 128, D2 / 128,
        out_b, out, input2, (long)D2 * TT);
}

// Round 15
// 560.447 us; speedup vs baseline: 1.0727x; 1.0727x over previous
//
#include <hip/hip_runtime.h>
#include <hip/hip_bf16.h>

#define BB 16
#define D1 1024
#define D2 1024
#define LL 512
#define TT 2048
#define LN_EPS 1e-5f

typedef unsigned short u16;
typedef __attribute__((ext_vector_type(8))) _Float16 half8;
typedef __attribute__((ext_vector_type(4))) float f32x4;
typedef __attribute__((ext_vector_type(4))) unsigned int u32x4;

__device__ __forceinline__ u16 f2h(float v) {
    _Float16 h = (_Float16)v;
    return *(u16*)&h;
}
__device__ __forceinline__ float h2f(u16 u) {
    return (float)(*(const _Float16*)&u);
}

__device__ __forceinline__ void gload_lds16(const void* g, void* l) {
    __builtin_amdgcn_global_load_lds((const __attribute__((address_space(1))) void*)g,
                                     (__attribute__((address_space(3))) void*)l, 16, 0, 0);
}

#define MEMFENCE asm volatile("" ::: "memory")
__device__ __forceinline__ void block_barrier() {
    MEMFENCE; __builtin_amdgcn_s_barrier(); MEMFENCE;
}

// ============================================================================
// BIG kernel (R12, best measured): 256x256 tile, BK=64, 512 threads (8 waves,
// 2Mx4N), double-buffered LDS, counted vmcnt(8). Projections + QK^T + PV.
// LNS=1 (with OMODE=1): accumulate LayerNorm sum/sumsq of C per batch.
// ============================================================================
template<int BIAS, int OMODE, int LNS>
__global__ __launch_bounds__(512, 2) void nt_gemm(
    const u16* __restrict__ A, const u16* __restrict__ B,
    long sAb, long sBb, long sCb,
    int N, int Kd, int gx, int gy,
    const float* __restrict__ bias,
    void* __restrict__ out0,
    const float* __restrict__ resid, long sRb,
    float* __restrict__ lnsums)
{
    __shared__ __align__(16) u16 smem[65536];

    const int nwg = gridDim.x;
    const int id = blockIdx.x;
    const int swz = (id & 7) * (nwg >> 3) + (id >> 3);
    const int bx = swz % gx;
    const int byz = swz / gx;
    const int by = byz % gy;
    const int b = byz / gy;

    const int tid = threadIdx.x;
    const long arow0 = (long)by * 256;
    const long brow0 = (long)bx * 256;
    const u16* Ab = A + (long)b * sAb + arow0 * Kd;
    const u16* Bb = B + (long)b * sBb + brow0 * Kd;

    const int wave = tid >> 6, lane = tid & 63;
    const int wm = (wave >> 2) * 128, wn = (wave & 3) * 64;
    const int lm = lane & 15, kg = lane >> 4;

    const int m0 = tid >> 3, s0 = tid & 7;
    const int nt = Kd >> 6;

    auto STAGE = [&](int buf, long k0) {
        u16* Ad = smem + buf * 32768;
        u16* Bd = smem + buf * 32768 + 16384;
#pragma unroll
        for (int call = 0; call < 4; ++call) {
            int m = call * 64 + m0;
            int gs = s0 ^ (m & 7);
            gload_lds16(Ab + k0 + (long)m * Kd + gs * 8, Ad + (call * 512 + tid) * 8);
        }
#pragma unroll
        for (int call = 0; call < 4; ++call) {
            int m = call * 64 + m0;
            int gs = s0 ^ (m & 7);
            gload_lds16(Bb + k0 + (long)m * Kd + gs * 8, Bd + (call * 512 + tid) * 8);
        }
    };

    f32x4 acc[8][4];
#pragma unroll
    for (int i = 0; i < 8; ++i)
#pragma unroll
        for (int j = 0; j < 4; ++j) acc[i][j] = (f32x4){0.f, 0.f, 0.f, 0.f};

    STAGE(0, 0);
    if (nt > 1) STAGE(1, 64);

    for (int t = 0; t < nt; ++t) {
        const int cur = t & 1;
        if (t + 1 < nt) { asm volatile("s_waitcnt vmcnt(8)" ::: "memory"); }
        else           { asm volatile("s_waitcnt vmcnt(0)" ::: "memory"); }
        block_barrier();

        const u16* Ac = smem + cur * 32768;
        const u16* Bc = smem + cur * 32768 + 16384;

        half8 bf[4][2];
#pragma unroll
        for (int f = 0; f < 4; ++f)
#pragma unroll
            for (int kf = 0; kf < 2; ++kf) {
                int nr = wn + f * 16 + lm;
                int ss = (kf * 4 + kg) ^ (nr & 7);
                bf[f][kf] = *(const half8*)(Bc + nr * 64 + ss * 8);
            }
#pragma unroll
        for (int mh = 0; mh < 2; ++mh) {
            half8 af[4][2];
#pragma unroll
            for (int f = 0; f < 4; ++f)
#pragma unroll
                for (int kf = 0; kf < 2; ++kf) {
                    int mr = wm + mh * 64 + f * 16 + lm;
                    int ss = (kf * 4 + kg) ^ (mr & 7);
                    af[f][kf] = *(const half8*)(Ac + mr * 64 + ss * 8);
                }
            __builtin_amdgcn_s_setprio(1);
#pragma unroll
            for (int f = 0; f < 4; ++f)
#pragma unroll
                for (int j = 0; j < 4; ++j)
#pragma unroll
                    for (int kf = 0; kf < 2; ++kf)
                        acc[mh * 4 + f][j] = __builtin_amdgcn_mfma_f32_16x16x32_f16(
                            af[f][kf], bf[j][kf], acc[mh * 4 + f][j], 0, 0, 0);
            __builtin_amdgcn_s_setprio(0);
        }
        block_barrier();
        if (t + 2 < nt) STAGE(cur, (long)(t + 2) * 64);
    }

    // ---- epilogue: LDS-staged (swizzled), coalesced stores; two 128-row passes ----
    float ls = 0.f, lsq = 0.f;
    float* Cs = (float*)smem;   // 128 x 256 fp32 = 128 KB
#pragma unroll
    for (int p = 0; p < 2; ++p) {
        __syncthreads();
        if (wm == p * 128) {
#pragma unroll
            for (int i = 0; i < 8; ++i)
#pragma unroll
                for (int j = 0; j < 4; ++j)
#pragma unroll
                    for (int r = 0; r < 4; ++r) {
                        int row = i * 16 + kg * 4 + r;
                        int col = wn + j * 16 + lm;
                        Cs[row * 256 + (col ^ ((row & 7) << 2))] = acc[i][j][r];
                    }
        }
        __syncthreads();
        if (OMODE == 0 || OMODE == 3) {
#pragma unroll
            for (int it = 0; it < 16; ++it) {
                int elem = it * 512 + tid;
                int row = elem >> 6, c4 = elem & 63;
                int grow = (int)arow0 + p * 128 + row;
                int gcol = (int)brow0 + c4 * 4;
                f32x4 v = *(const f32x4*)&Cs[row * 256 + ((c4 ^ (row & 7)) << 2)];
                if (BIAS == 1) v += bias[grow];
                if (BIAS == 2) v += *(const f32x4*)(bias + gcol);
                long off = (long)b * sCb + (long)grow * N + gcol;
                if (OMODE == 3) {
                    f32x4 rv = __builtin_nontemporal_load(
                        (const f32x4*)(resid + (long)b * sRb + (long)grow * N + gcol));
                    v += rv;
                    __builtin_nontemporal_store(v, (f32x4*)((float*)out0 + off));
                } else {
                    *(f32x4*)((float*)out0 + off) = v;   // reused intermediate: cached
                }
            }
        } else {
#pragma unroll
            for (int it = 0; it < 8; ++it) {
                int elem = it * 512 + tid;
                int row = elem >> 5, c8 = elem & 31;
                int grow = (int)arow0 + p * 128 + row;
                int gcol = (int)brow0 + c8 * 8;
                int g0 = (c8 * 2) ^ (row & 7);
                int g1 = (c8 * 2 + 1) ^ (row & 7);
                f32x4 u0 = *(const f32x4*)&Cs[row * 256 + g0 * 4];
                f32x4 u1 = *(const f32x4*)&Cs[row * 256 + g1 * 4];
                float vv[8] = {u0.x, u0.y, u0.z, u0.w, u1.x, u1.y, u1.z, u1.w};
                if (BIAS == 1) {
                    float bb = bias[grow];
#pragma unroll
                    for (int q = 0; q < 8; ++q) vv[q] += bb;
                }
                if (BIAS == 2) {
#pragma unroll
                    for (int q = 0; q < 8; ++q) vv[q] += bias[gcol + q];
                }
                if (LNS) {
#pragma unroll
                    for (int q = 0; q < 8; ++q) { ls += vv[q]; lsq += vv[q] * vv[q]; }
                }
                union { u16 u[8]; u32x4 v4; } pk;
#pragma unroll
                for (int q = 0; q < 8; ++q) pk.u[q] = f2h(vv[q]);
                long off = (long)b * sCb + (long)grow * N + gcol;
                *(u32x4*)((u16*)out0 + off) = pk.v4;   // reused intermediate: cached
            }
        }
    }
    if (LNS) {
#pragma unroll
        for (int off = 32; off; off >>= 1) {
            ls += __shfl_xor(ls, off, 64);
            lsq += __shfl_xor(lsq, off, 64);
        }
        __shared__ float rsum[16];
        if (lane == 0) { rsum[wave] = ls; rsum[8 + wave] = lsq; }
        __syncthreads();
        if (tid == 0) {
            float a = 0.f, c = 0.f;
#pragma unroll
            for (int w = 0; w < 8; ++w) { a += rsum[w]; c += rsum[8 + w]; }
            atomicAdd(&lnsums[b * 2], a);
            atomicAdd(&lnsums[b * 2 + 1], c);
        }
    }
}

// ============================================================================
// SMALL kernel: 128x128, BK=64, 256 thr, 32KB LDS, 4 blocks/CU (measured
// best; 5 blocks/CU forces VGPR<64 -> accumulator spills, +42us).
// For the memory-bound out-proj.
// ============================================================================
__device__ __forceinline__ void stage_tile_sm(const u16* __restrict__ g, int ldk, u16* lds, int tid) {
#pragma unroll
    for (int it = 0; it < 4; ++it) {
        int idx = it * 256 + tid;
        int m = idx >> 3, s = idx & 7;
        int gs = s ^ (m & 7);
        gload_lds16(g + (long)m * ldk + gs * 8, lds + idx * 8);
    }
}

template<int BIAS, int OMODE>
__global__ __launch_bounds__(256, 4) void nt_gemm_sm(
    const u16* __restrict__ A, const u16* __restrict__ B,
    long sAb, long sBb, long sCb,
    int N, int Kd, int gx, int gy,
    const float* __restrict__ bias,
    void* __restrict__ out0,
    const float* __restrict__ resid, long sRb)
{
    __shared__ __align__(16) u16 smem[2 * 128 * 64];
    u16* As = smem;
    u16* Bs = smem + 128 * 64;

    const int nwg = gridDim.x;
    const int id = blockIdx.x;
    const int swz = (id & 7) * (nwg >> 3) + (id >> 3);
    const int bx = swz % gx;
    const int byz = swz / gx;
    const int by = byz % gy;
    const int b = byz / gy;

    const int tid = threadIdx.x;
    const long arow0 = (long)by * 128;
    const long brow0 = (long)bx * 128;
    const u16* Ab = A + (long)b * sAb + arow0 * Kd;
    const u16* Bb = B + (long)b * sBb + brow0 * Kd;

    const int wave = tid >> 6, lane = tid & 63;
    const int wm = (wave >> 1) * 64, wn = (wave & 1) * 64;
    const int lm = lane & 15, kg = lane >> 4;

    f32x4 acc[4][4];
#pragma unroll
    for (int i = 0; i < 4; ++i)
#pragma unroll
        for (int j = 0; j < 4; ++j) acc[i][j] = (f32x4){0.f, 0.f, 0.f, 0.f};

    for (int k0 = 0; k0 < Kd; k0 += 64) {
        stage_tile_sm(Ab + k0, Kd, As, tid);
        stage_tile_sm(Bb + k0, Kd, Bs, tid);
        __syncthreads();
#pragma unroll
        for (int ks = 0; ks < 2; ++ks) {
            half8 af[4], bf[4];
#pragma unroll
            for (int f = 0; f < 4; ++f) {
                int mr = wm + f * 16 + lm;
                int as_ = (ks * 4 + kg) ^ (mr & 7);
                af[f] = *(const half8*)(As + mr * 64 + as_ * 8);
                int nr = wn + f * 16 + lm;
                int bs_ = (ks * 4 + kg) ^ (nr & 7);
                bf[f] = *(const half8*)(Bs + nr * 64 + bs_ * 8);
            }
#pragma unroll
            for (int i = 0; i < 4; ++i)
#pragma unroll
                for (int j = 0; j < 4; ++j)
                    acc[i][j] = __builtin_amdgcn_mfma_f32_16x16x32_f16(af[i], bf[j], acc[i][j], 0, 0, 0);
        }
        __syncthreads();
    }

    float* Cs = (float*)smem;
#pragma unroll
    for (int p = 0; p < 2; ++p) {
        if (p) __syncthreads();
        if (wm == p * 64) {
#pragma unroll
            for (int i = 0; i < 4; ++i)
#pragma unroll
                for (int j = 0; j < 4; ++j)
#pragma unroll
                    for (int r = 0; r < 4; ++r) {
                        int row = i * 16 + kg * 4 + r;
                        int col = wn + j * 16 + lm;
                        Cs[row * 128 + (col ^ ((row & 7) << 2))] = acc[i][j][r];
                    }
        }
        __syncthreads();
        if (OMODE == 0 || OMODE == 3) {
#pragma unroll
            for (int rr = 0; rr < 8; ++rr) {
                int elem = rr * 256 + tid;
                int row = elem >> 5, c4 = elem & 31;
                int grow = (int)arow0 + p * 64 + row;
                int gcol = (int)brow0 + c4 * 4;
                f32x4 v = *(const f32x4*)&Cs[row * 128 + ((c4 ^ (row & 7)) << 2)];
                if (BIAS == 1) v += bias[grow];
                if (BIAS == 2) v += *(const f32x4*)(bias + gcol);
                long off = (long)b * sCb + (long)grow * N + gcol;
                if (OMODE == 3) {
                    f32x4 rv = __builtin_nontemporal_load(
                        (const f32x4*)(resid + (long)b * sRb + (long)grow * N + gcol));
                    v += rv;
                    __builtin_nontemporal_store(v, (f32x4*)((float*)out0 + off));
                } else {
                    *(f32x4*)((float*)out0 + off) = v;
                }
            }
        } else {
#pragma unroll
            for (int rr = 0; rr < 4; ++rr) {
                int elem = rr * 256 + tid;
                int row = elem >> 4, c8 = elem & 15;
                int grow = (int)arow0 + p * 64 + row;
                int gcol = (int)brow0 + c8 * 8;
                int g0 = (c8 * 2) ^ (row & 7);
                int g1 = (c8 * 2 + 1) ^ (row & 7);
                f32x4 u0 = *(const f32x4*)&Cs[row * 128 + g0 * 4];
                f32x4 u1 = *(const f32x4*)&Cs[row * 128 + g1 * 4];
                float vv[8] = {u0.x, u0.y, u0.z, u0.w, u1.x, u1.y, u1.z, u1.w};
                if (BIAS == 1) {
                    float bb = bias[grow];
#pragma unroll
                    for (int q = 0; q < 8; ++q) vv[q] += bb;
                }
                if (BIAS == 2) {
#pragma unroll
                    for (int q = 0; q < 8; ++q) vv[q] += bias[gcol + q];
                }
                union { u16 u[8]; u32x4 v4; } pk;
#pragma unroll
                for (int q = 0; q < 8; ++q) pk.u[q] = f2h(vv[q]);
                long off = (long)b * sCb + (long)grow * N + gcol;
                *(u32x4*)((u16*)out0 + off) = pk.v4;
            }
        }
    }
}

// fp32 [D][T] (per batch) -> fp16 [T][D], vectorized 16B/lane writes
__global__ __launch_bounds__(256) void transpose_h(const float* __restrict__ in,
                                                   u16* __restrict__ o16, int D, int T) {
    __shared__ float tile[64][65];
    int b = blockIdx.z;
    const float* src = in + (long)b * D * T;
    long obase = (long)b * D * T;
    int t0 = blockIdx.x * 64, d0 = blockIdx.y * 64;
    int tx = threadIdx.x & 63, ty = threadIdx.x >> 6;
#pragma unroll
    for (int i = 0; i < 64; i += 4)
        tile[ty + i][tx] = __builtin_nontemporal_load(&src[(long)(d0 + ty + i) * T + t0 + tx]);
    __syncthreads();
    // each item = one t-row x 8 consecutive d -> one 16B store (full lines per 8 lanes)
#pragma unroll
    for (int it = 0; it < 2; ++it) {
        int item = it * 256 + threadIdx.x;   // 0..511
        int tl = item >> 3, dc = item & 7;
        union { u16 u[8]; u32x4 v4; } pk;
#pragma unroll
        for (int q = 0; q < 8; ++q) pk.u[q] = f2h(tile[dc * 8 + q][tl]);
        *(u32x4*)(o16 + obase + (long)(t0 + tl) * D + d0 + dc * 8) = pk.v4;
    }
}

// fp32 [R][C] -> fp32 [C][R]
__global__ __launch_bounds__(256) void transpose_f32(const float* __restrict__ in,
                                                     float* __restrict__ out, int R, int C) {
    __shared__ float tile[64][65];
    int c0 = blockIdx.x * 64, r0 = blockIdx.y * 64;
    int tx = threadIdx.x & 63, ty = threadIdx.x >> 6;
#pragma unroll
    for (int i = 0; i < 64; i += 4)
        tile[ty + i][tx] = in[(long)(r0 + ty + i) * C + c0 + tx];
    __syncthreads();
#pragma unroll
    for (int i = 0; i < 64; i += 4)
        out[(long)(c0 + ty + i) * R + r0 + tx] = tile[tx][ty + i];
}

__global__ __launch_bounds__(256) void conv_w(const float* __restrict__ w,
                                              u16* __restrict__ h, int n) {
    int i = blockIdx.x * 256 + threadIdx.x;
    if (i < n) h[i] = f2h(w[i]);
}

// one block per score row (2048 cols), fp32 in (L3-resident), fp16 prob out
__global__ __launch_bounds__(256) void softmax_rows(const float* __restrict__ S, u16* __restrict__ P) {
    long row = (long)blockIdx.z * TT + blockIdx.x;
    const float* s = S + row * TT;
    u16* p = P + row * TT;
    int tid = threadIdx.x;
    f32x4 v0 = *(const f32x4*)(s + tid * 8);
    f32x4 v1 = *(const f32x4*)(s + tid * 8 + 4);
    float x[8] = {v0.x, v0.y, v0.z, v0.w, v1.x, v1.y, v1.z, v1.w};
    float m = x[0];
#pragma unroll
    for (int j = 1; j < 8; ++j) m = fmaxf(m, x[j]);
#pragma unroll
    for (int off = 32; off; off >>= 1) m = fmaxf(m, __shfl_xor(m, off, 64));
    __shared__ float red[8];
    int wave = tid >> 6, lane = tid & 63;
    if (lane == 0) red[wave] = m;
    __syncthreads();
    m = fmaxf(fmaxf(red[0], red[1]), fmaxf(red[2], red[3]));
    float e[8]; float sum = 0.f;
#pragma unroll
    for (int j = 0; j < 8; ++j) { e[j] = __expf(x[j] - m); sum += e[j]; }
#pragma unroll
    for (int off = 32; off; off >>= 1) sum += __shfl_xor(sum, off, 64);
    if (lane == 0) red[4 + wave] = sum;
    __syncthreads();
    sum = red[4] + red[5] + red[6] + red[7];
    float inv = 1.f / sum;
    union { u16 u[8]; u32x4 v4; } pk;
#pragma unroll
    for (int j = 0; j < 8; ++j) pk.u[j] = f2h(e[j] * inv);
    *(u32x4*)(p + tid * 8) = pk.v4;
}

__global__ void zero32(float* p) { p[threadIdx.x] = 0.f; }

__global__ __launch_bounds__(256) void ln_apply(const u16* __restrict__ TXp, const float* __restrict__ sums,
                                                const float* __restrict__ gT, const float* __restrict__ bT,
                                                u16* __restrict__ H) {
    int b = blockIdx.z;
    const float n = (float)(LL * TT);
    float mu = sums[b * 2] / n;
    float var = sums[b * 2 + 1] / n - mu * mu;
    float rstd = rsqrtf(var + LN_EPS);
    long base = (long)b * (LL * TT);
    long idx = ((long)blockIdx.x * 256 + threadIdx.x) * 8;
    u32x4 xv = *(const u32x4*)(TXp + base + idx);
    unsigned w[4] = {xv.x, xv.y, xv.z, xv.w};
    f32x4 g0 = *(const f32x4*)(gT + idx);
    f32x4 g1 = *(const f32x4*)(gT + idx + 4);
    f32x4 b0 = *(const f32x4*)(bT + idx);
    f32x4 b1 = *(const f32x4*)(bT + idx + 4);
    float g[8] = {g0.x, g0.y, g0.z, g0.w, g1.x, g1.y, g1.z, g1.w};
    float be[8] = {b0.x, b0.y, b0.z, b0.w, b1.x, b1.y, b1.z, b1.w};
    union { u16 u[8]; u32x4 v; } pk;
#pragma unroll
    for (int q = 0; q < 4; ++q) {
        float a = h2f((u16)(w[q] & 0xffff));
        float c = h2f((u16)(w[q] >> 16));
        float oa = fmaxf((a - mu) * rstd * g[q * 2] + be[q * 2], 0.f);
        float oc = fmaxf((c - mu) * rstd * g[q * 2 + 1] + be[q * 2 + 1], 0.f);
        pk.u[q * 2] = f2h(oa);
        pk.u[q * 2 + 1] = f2h(oc);
    }
    *(u32x4*)(H + base + idx) = pk.v;
}

extern "C" void kernel_launch(void* const* d_in, const int* in_sizes, int n_in,
                              void* d_out, int out_size, void* d_ws, size_t ws_size,
                              hipStream_t stream) {
    const float* input1  = (const float*)d_in[0];
    const float* input2  = (const float*)d_in[1];
    const float* theta_w = (const float*)d_in[2];
    const float* theta_b = (const float*)d_in[3];
    const float* phi_w   = (const float*)d_in[4];
    const float* phi_b   = (const float*)d_in[5];
    const float* g_w     = (const float*)d_in[6];
    const float* g_b     = (const float*)d_in[7];
    const float* ln_gamma= (const float*)d_in[8];
    const float* ln_beta = (const float*)d_in[9];
    const float* out_w   = (const float*)d_in[10];
    const float* out_b   = (const float*)d_in[11];
    float* out = (float*)d_out;

    char* ws = (char*)d_ws;
    const size_t MB = 1ull << 20;
    u16*  Xt     = (u16*)(ws + 0);          // 64MB [B][T][1024] fp16 (dead after projections)
    float* scores= (float*)(ws + 0);        // 64MB [4][T][T] fp32 (reuses Xt region, L3-resident)
    u16*  pmat   = (u16*)(ws + 64 * MB);    // 128MB [16][T][T] fp16
    u16*  Qf     = (u16*)(ws + 192 * MB);   // 32MB [B][T][L]
    u16*  Kf     = (u16*)(ws + 224 * MB);   // 32MB [B][T][L]
    u16*  Vt     = (u16*)(ws + 256 * MB);   // 32MB [B][L][T]
    u16*  TX     = (u16*)(ws + 288 * MB);   // 32MB [B][T][L] fp16
    u16*  H      = (u16*)(ws + 320 * MB);   // 32MB [B][T][L]
    u16*  thw    = (u16*)(ws + 352 * MB);   // 1MB each
    u16*  phw    = (u16*)(ws + 353 * MB);
    u16*  gww    = (u16*)(ws + 354 * MB);
    u16*  oww    = (u16*)(ws + 355 * MB);
    float* gammaT= (float*)(ws + 356 * MB); // 4MB [T][L]
    float* betaT = (float*)(ws + 360 * MB); // 4MB
    float* sums  = (float*)(ws + 364 * MB); // 128B

    dim3 blk(256), blk5(512);

    conv_w<<<dim3((LL * D2 + 255) / 256), blk, 0, stream>>>(theta_w, thw, LL * D2);
    conv_w<<<dim3((LL * D1 + 255) / 256), blk, 0, stream>>>(phi_w, phw, LL * D1);
    conv_w<<<dim3((LL * D1 + 255) / 256), blk, 0, stream>>>(g_w, gww, LL * D1);
    conv_w<<<dim3((D2 * LL + 255) / 256), blk, 0, stream>>>(out_w, oww, D2 * LL);
    transpose_f32<<<dim3(TT / 64, LL / 64, 1), blk, 0, stream>>>(ln_gamma, gammaT, LL, TT);
    transpose_f32<<<dim3(TT / 64, LL / 64, 1), blk, 0, stream>>>(ln_beta, betaT, LL, TT);
    zero32<<<dim3(1), dim3(32), 0, stream>>>(sums);

    // Q = theta(input2)
    transpose_h<<<dim3(TT / 64, D2 / 64, BB), blk, 0, stream>>>(input2, Xt, D2, TT);
    nt_gemm<2, 1, 0><<<dim3((LL / 256) * (TT / 256) * BB), blk5, 0, stream>>>(
        Xt, thw, (long)TT * D2, 0, (long)TT * LL, LL, D2, LL / 256, TT / 256,
        theta_b, Qf, nullptr, 0, nullptr);

    // K = phi(input1), V^T = g(input1)
    transpose_h<<<dim3(TT / 64, D1 / 64, BB), blk, 0, stream>>>(input1, Xt, D1, TT);
    nt_gemm<2, 1, 0><<<dim3((LL / 256) * (TT / 256) * BB), blk5, 0, stream>>>(
        Xt, phw, (long)TT * D1, 0, (long)TT * LL, LL, D1, LL / 256, TT / 256,
        phi_b, Kf, nullptr, 0, nullptr);
    nt_gemm<1, 1, 0><<<dim3((TT / 256) * (LL / 256) * BB), blk5, 0, stream>>>(
        gww, Xt, 0, (long)TT * D1, (long)LL * TT, TT, D1, TT / 256, LL / 256,
        g_b, Vt, nullptr, 0, nullptr);

    // attention scores+softmax, 4 batches per chunk (scores reuse Xt region)
    for (int c = 0; c < 4; ++c) {
        long qoff = (long)c * 4 * TT * LL;
        nt_gemm<0, 0, 0><<<dim3((TT / 256) * (TT / 256) * 4), blk5, 0, stream>>>(
            Qf + qoff, Kf + qoff, (long)TT * LL, (long)TT * LL, (long)TT * TT,
            TT, LL, TT / 256, TT / 256, nullptr, scores, nullptr, 0, nullptr);
        softmax_rows<<<dim3(TT, 1, 4), blk, 0, stream>>>(scores, pmat + (long)c * 4 * TT * TT);
    }
    // PV: one full-GPU dispatch over all 16 batches, LayerNorm sums fused
    nt_gemm<0, 1, 1><<<dim3((LL / 256) * (TT / 256) * BB), blk5, 0, stream>>>(
        pmat, Vt, (long)TT * TT, (long)LL * TT, (long)TT * LL,
        LL, TT, LL / 256, TT / 256, nullptr, TX, nullptr, 0, sums);

    ln_apply<<<dim3(512, 1, BB), blk, 0, stream>>>(TX, sums, gammaT, betaT, H);

    // out = out_w * h + out_b + input2  (small kernel, 4 blocks/CU — measured best)
    nt_gemm_sm<1, 3><<<dim3((TT / 128) * (D2 / 128) * BB), blk, 0, stream>>>(
        oww, H, 0, (long)TT * LL, (long)D2 * TT, TT, LL, TT / 128, D2 / 128,
        out_b, out, input2, (long)D2 * TT);
}

// Round 16
// 540.551 us; speedup vs baseline: 1.1122x; 1.0368x over previous
//
#include <hip/hip_runtime.h>
#include <hip/hip_bf16.h>

#define BB 16
#define D1 1024
#define D2 1024
#define LL 512
#define TT 2048
#define LN_EPS 1e-5f

typedef unsigned short u16;
typedef __attribute__((ext_vector_type(8))) _Float16 half8;
typedef __attribute__((ext_vector_type(4))) float f32x4;
typedef __attribute__((ext_vector_type(4))) unsigned int u32x4;

__device__ __forceinline__ u16 f2h(float v) {
    _Float16 h = (_Float16)v;
    return *(u16*)&h;
}
__device__ __forceinline__ float h2f(u16 u) {
    return (float)(*(const _Float16*)&u);
}

__device__ __forceinline__ void gload_lds16(const void* g, void* l) {
    __builtin_amdgcn_global_load_lds((const __attribute__((address_space(1))) void*)g,
                                     (__attribute__((address_space(3))) void*)l, 16, 0, 0);
}

#define MEMFENCE asm volatile("" ::: "memory")
__device__ __forceinline__ void block_barrier() {
    MEMFENCE; __builtin_amdgcn_s_barrier(); MEMFENCE;
}

// ============================================================================
// BIG kernel: 256x256 tile, BK=64, 1024 threads = 16 waves (4Mx4N, 64x64 per
// wave -> 4 waves/SIMD, 2x the TLP of the 8-wave version). 2-phase K-loop,
// double-buffered LDS, counted vmcnt(4). Per-kf fragment loads keep VGPR
// liveness ~116 (<128 hard cap for 1024-thr blocks).
// LNS=1 (with OMODE=1): accumulate LayerNorm sum/sumsq of C per batch.
// ============================================================================
template<int BIAS, int OMODE, int LNS>
__global__ __launch_bounds__(1024, 4) void nt_gemm(
    const u16* __restrict__ A, const u16* __restrict__ B,
    long sAb, long sBb, long sCb,
    int N, int Kd, int gx, int gy,
    const float* __restrict__ bias,
    void* __restrict__ out0,
    const float* __restrict__ resid, long sRb,
    float* __restrict__ lnsums)
{
    __shared__ __align__(16) u16 smem[65536];

    const int nwg = gridDim.x;
    const int id = blockIdx.x;
    const int swz = (id & 7) * (nwg >> 3) + (id >> 3);
    const int bx = swz % gx;
    const int byz = swz / gx;
    const int by = byz % gy;
    const int b = byz / gy;

    const int tid = threadIdx.x;
    const long arow0 = (long)by * 256;
    const long brow0 = (long)bx * 256;
    const u16* Ab = A + (long)b * sAb + arow0 * Kd;
    const u16* Bb = B + (long)b * sBb + brow0 * Kd;

    const int wave = tid >> 6, lane = tid & 63;
    const int wm = (wave >> 2) * 64, wn = (wave & 3) * 64;
    const int lm = lane & 15, kg = lane >> 4;

    const int nt = Kd >> 6;

    // stage 256x64 A + 256x64 B (4 loads/thread @1024 threads)
    auto STAGE = [&](int buf, long k0) {
        u16* Ad = smem + buf * 32768;
        u16* Bd = smem + buf * 32768 + 16384;
#pragma unroll
        for (int call = 0; call < 2; ++call) {
            int idx = call * 1024 + tid;
            int m = idx >> 3, s = idx & 7;
            int gs = s ^ (m & 7);
            gload_lds16(Ab + k0 + (long)m * Kd + gs * 8, Ad + idx * 8);
        }
#pragma unroll
        for (int call = 0; call < 2; ++call) {
            int idx = call * 1024 + tid;
            int m = idx >> 3, s = idx & 7;
            int gs = s ^ (m & 7);
            gload_lds16(Bb + k0 + (long)m * Kd + gs * 8, Bd + idx * 8);
        }
    };

    f32x4 acc[4][4];
#pragma unroll
    for (int i = 0; i < 4; ++i)
#pragma unroll
        for (int j = 0; j < 4; ++j) acc[i][j] = (f32x4){0.f, 0.f, 0.f, 0.f};

    STAGE(0, 0);
    if (nt > 1) STAGE(1, 64);

    for (int t = 0; t < nt; ++t) {
        const int cur = t & 1;
        if (t + 1 < nt) { asm volatile("s_waitcnt vmcnt(4)" ::: "memory"); }
        else           { asm volatile("s_waitcnt vmcnt(0)" ::: "memory"); }
        block_barrier();

        const u16* Ac = smem + cur * 32768;
        const u16* Bc = smem + cur * 32768 + 16384;

#pragma unroll
        for (int kf = 0; kf < 2; ++kf) {
            half8 af[4], bf[4];
#pragma unroll
            for (int f = 0; f < 4; ++f) {
                int nr = wn + f * 16 + lm;
                int ssb = (kf * 4 + kg) ^ (nr & 7);
                bf[f] = *(const half8*)(Bc + nr * 64 + ssb * 8);
                int mr = wm + f * 16 + lm;
                int ssa = (kf * 4 + kg) ^ (mr & 7);
                af[f] = *(const half8*)(Ac + mr * 64 + ssa * 8);
            }
            __builtin_amdgcn_s_setprio(1);
#pragma unroll
            for (int i = 0; i < 4; ++i)
#pragma unroll
                for (int j = 0; j < 4; ++j)
                    acc[i][j] = __builtin_amdgcn_mfma_f32_16x16x32_f16(
                        af[i], bf[j], acc[i][j], 0, 0, 0);
            __builtin_amdgcn_s_setprio(0);
        }
        block_barrier();
        if (t + 2 < nt) STAGE(cur, (long)(t + 2) * 64);
    }

    // ---- epilogue: LDS-staged (swizzled), coalesced stores; two 128-row passes ----
    float ls = 0.f, lsq = 0.f;
    float* Cs = (float*)smem;   // 128 x 256 fp32 = 128 KB
#pragma unroll
    for (int p = 0; p < 2; ++p) {
        __syncthreads();
        if ((wm >> 7) == p) {
#pragma unroll
            for (int i = 0; i < 4; ++i)
#pragma unroll
                for (int j = 0; j < 4; ++j)
#pragma unroll
                    for (int r = 0; r < 4; ++r) {
                        int row = (wm & 64) + i * 16 + kg * 4 + r;
                        int col = wn + j * 16 + lm;
                        Cs[row * 256 + (col ^ ((row & 7) << 2))] = acc[i][j][r];
                    }
        }
        __syncthreads();
        if (OMODE == 0 || OMODE == 3) {
#pragma unroll
            for (int it = 0; it < 8; ++it) {
                int elem = it * 1024 + tid;
                int row = elem >> 6, c4 = elem & 63;
                int grow = (int)arow0 + p * 128 + row;
                int gcol = (int)brow0 + c4 * 4;
                f32x4 v = *(const f32x4*)&Cs[row * 256 + ((c4 ^ (row & 7)) << 2)];
                if (BIAS == 1) v += bias[grow];
                if (BIAS == 2) v += *(const f32x4*)(bias + gcol);
                long off = (long)b * sCb + (long)grow * N + gcol;
                if (OMODE == 3) {
                    f32x4 rv = __builtin_nontemporal_load(
                        (const f32x4*)(resid + (long)b * sRb + (long)grow * N + gcol));
                    v += rv;
                    __builtin_nontemporal_store(v, (f32x4*)((float*)out0 + off));
                } else {
                    *(f32x4*)((float*)out0 + off) = v;   // reused intermediate: cached
                }
            }
        } else {
#pragma unroll
            for (int it = 0; it < 4; ++it) {
                int elem = it * 1024 + tid;
                int row = elem >> 5, c8 = elem & 31;
                int grow = (int)arow0 + p * 128 + row;
                int gcol = (int)brow0 + c8 * 8;
                int g0 = (c8 * 2) ^ (row & 7);
                int g1 = (c8 * 2 + 1) ^ (row & 7);
                f32x4 u0 = *(const f32x4*)&Cs[row * 256 + g0 * 4];
                f32x4 u1 = *(const f32x4*)&Cs[row * 256 + g1 * 4];
                float vv[8] = {u0.x, u0.y, u0.z, u0.w, u1.x, u1.y, u1.z, u1.w};
                if (BIAS == 1) {
                    float bb = bias[grow];
#pragma unroll
                    for (int q = 0; q < 8; ++q) vv[q] += bb;
                }
                if (BIAS == 2) {
#pragma unroll
                    for (int q = 0; q < 8; ++q) vv[q] += bias[gcol + q];
                }
                if (LNS) {
#pragma unroll
                    for (int q = 0; q < 8; ++q) { ls += vv[q]; lsq += vv[q] * vv[q]; }
                }
                union { u16 u[8]; u32x4 v4; } pk;
#pragma unroll
                for (int q = 0; q < 8; ++q) pk.u[q] = f2h(vv[q]);
                long off = (long)b * sCb + (long)grow * N + gcol;
                *(u32x4*)((u16*)out0 + off) = pk.v4;   // reused intermediate: cached
            }
        }
    }
    if (LNS) {
#pragma unroll
        for (int off = 32; off; off >>= 1) {
            ls += __shfl_xor(ls, off, 64);
            lsq += __shfl_xor(lsq, off, 64);
        }
        __shared__ float rsum[32];
        if (lane == 0) { rsum[wave] = ls; rsum[16 + wave] = lsq; }
        __syncthreads();
        if (tid == 0) {
            float a = 0.f, c = 0.f;
#pragma unroll
            for (int w = 0; w < 16; ++w) { a += rsum[w]; c += rsum[16 + w]; }
            atomicAdd(&lnsums[b * 2], a);
            atomicAdd(&lnsums[b * 2 + 1], c);
        }
    }
}

// ============================================================================
// SMALL kernel: 128x128, BK=64, 256 thr, 32KB LDS, 4 blocks/CU (measured
// best; 5 blocks/CU forces VGPR<64 -> accumulator spills, +42us).
// For the memory-bound out-proj.
// ============================================================================
__device__ __forceinline__ void stage_tile_sm(const u16* __restrict__ g, int ldk, u16* lds, int tid) {
#pragma unroll
    for (int it = 0; it < 4; ++it) {
        int idx = it * 256 + tid;
        int m = idx >> 3, s = idx & 7;
        int gs = s ^ (m & 7);
        gload_lds16(g + (long)m * ldk + gs * 8, lds + idx * 8);
    }
}

template<int BIAS, int OMODE>
__global__ __launch_bounds__(256, 4) void nt_gemm_sm(
    const u16* __restrict__ A, const u16* __restrict__ B,
    long sAb, long sBb, long sCb,
    int N, int Kd, int gx, int gy,
    const float* __restrict__ bias,
    void* __restrict__ out0,
    const float* __restrict__ resid, long sRb)
{
    __shared__ __align__(16) u16 smem[2 * 128 * 64];
    u16* As = smem;
    u16* Bs = smem + 128 * 64;

    const int nwg = gridDim.x;
    const int id = blockIdx.x;
    const int swz = (id & 7) * (nwg >> 3) + (id >> 3);
    const int bx = swz % gx;
    const int byz = swz / gx;
    const int by = byz % gy;
    const int b = byz / gy;

    const int tid = threadIdx.x;
    const long arow0 = (long)by * 128;
    const long brow0 = (long)bx * 128;
    const u16* Ab = A + (long)b * sAb + arow0 * Kd;
    const u16* Bb = B + (long)b * sBb + brow0 * Kd;

    const int wave = tid >> 6, lane = tid & 63;
    const int wm = (wave >> 1) * 64, wn = (wave & 1) * 64;
    const int lm = lane & 15, kg = lane >> 4;

    f32x4 acc[4][4];
#pragma unroll
    for (int i = 0; i < 4; ++i)
#pragma unroll
        for (int j = 0; j < 4; ++j) acc[i][j] = (f32x4){0.f, 0.f, 0.f, 0.f};

    for (int k0 = 0; k0 < Kd; k0 += 64) {
        stage_tile_sm(Ab + k0, Kd, As, tid);
        stage_tile_sm(Bb + k0, Kd, Bs, tid);
        __syncthreads();
#pragma unroll
        for (int ks = 0; ks < 2; ++ks) {
            half8 af[4], bf[4];
#pragma unroll
            for (int f = 0; f < 4; ++f) {
                int mr = wm + f * 16 + lm;
                int as_ = (ks * 4 + kg) ^ (mr & 7);
                af[f] = *(const half8*)(As + mr * 64 + as_ * 8);
                int nr = wn + f * 16 + lm;
                int bs_ = (ks * 4 + kg) ^ (nr & 7);
                bf[f] = *(const half8*)(Bs + nr * 64 + bs_ * 8);
            }
#pragma unroll
            for (int i = 0; i < 4; ++i)
#pragma unroll
                for (int j = 0; j < 4; ++j)
                    acc[i][j] = __builtin_amdgcn_mfma_f32_16x16x32_f16(af[i], bf[j], acc[i][j], 0, 0, 0);
        }
        __syncthreads();
    }

    float* Cs = (float*)smem;
#pragma unroll
    for (int p = 0; p < 2; ++p) {
        if (p) __syncthreads();
        if (wm == p * 64) {
#pragma unroll
            for (int i = 0; i < 4; ++i)
#pragma unroll
                for (int j = 0; j < 4; ++j)
#pragma unroll
                    for (int r = 0; r < 4; ++r) {
                        int row = i * 16 + kg * 4 + r;
                        int col = wn + j * 16 + lm;
                        Cs[row * 128 + (col ^ ((row & 7) << 2))] = acc[i][j][r];
                    }
        }
        __syncthreads();
        if (OMODE == 0 || OMODE == 3) {
#pragma unroll
            for (int rr = 0; rr < 8; ++rr) {
                int elem = rr * 256 + tid;
                int row = elem >> 5, c4 = elem & 31;
                int grow = (int)arow0 + p * 64 + row;
                int gcol = (int)brow0 + c4 * 4;
                f32x4 v = *(const f32x4*)&Cs[row * 128 + ((c4 ^ (row & 7)) << 2)];
                if (BIAS == 1) v += bias[grow];
                if (BIAS == 2) v += *(const f32x4*)(bias + gcol);
                long off = (long)b * sCb + (long)grow * N + gcol;
                if (OMODE == 3) {
                    f32x4 rv = __builtin_nontemporal_load(
                        (const f32x4*)(resid + (long)b * sRb + (long)grow * N + gcol));
                    v += rv;
                    __builtin_nontemporal_store(v, (f32x4*)((float*)out0 + off));
                } else {
                    *(f32x4*)((float*)out0 + off) = v;
                }
            }
        } else {
#pragma unroll
            for (int rr = 0; rr < 4; ++rr) {
                int elem = rr * 256 + tid;
                int row = elem >> 4, c8 = elem & 15;
                int grow = (int)arow0 + p * 64 + row;
                int gcol = (int)brow0 + c8 * 8;
                int g0 = (c8 * 2) ^ (row & 7);
                int g1 = (c8 * 2 + 1) ^ (row & 7);
                f32x4 u0 = *(const f32x4*)&Cs[row * 128 + g0 * 4];
                f32x4 u1 = *(const f32x4*)&Cs[row * 128 + g1 * 4];
                float vv[8] = {u0.x, u0.y, u0.z, u0.w, u1.x, u1.y, u1.z, u1.w};
                if (BIAS == 1) {
                    float bb = bias[grow];
#pragma unroll
                    for (int q = 0; q < 8; ++q) vv[q] += bb;
                }
                if (BIAS == 2) {
#pragma unroll
                    for (int q = 0; q < 8; ++q) vv[q] += bias[gcol + q];
                }
                union { u16 u[8]; u32x4 v4; } pk;
#pragma unroll
                for (int q = 0; q < 8; ++q) pk.u[q] = f2h(vv[q]);
                long off = (long)b * sCb + (long)grow * N + gcol;
                *(u32x4*)((u16*)out0 + off) = pk.v4;
            }
        }
    }
}

// fp32 [D][T] (per batch) -> fp16 [T][D], vectorized 16B/lane writes
__global__ __launch_bounds__(256) void transpose_h(const float* __restrict__ in,
                                                   u16* __restrict__ o16, int D, int T) {
    __shared__ float tile[64][65];
    int b = blockIdx.z;
    const float* src = in + (long)b * D * T;
    long obase = (long)b * D * T;
    int t0 = blockIdx.x * 64, d0 = blockIdx.y * 64;
    int tx = threadIdx.x & 63, ty = threadIdx.x >> 6;
#pragma unroll
    for (int i = 0; i < 64; i += 4)
        tile[ty + i][tx] = __builtin_nontemporal_load(&src[(long)(d0 + ty + i) * T + t0 + tx]);
    __syncthreads();
#pragma unroll
    for (int it = 0; it < 2; ++it) {
        int item = it * 256 + threadIdx.x;   // 0..511
        int tl = item >> 3, dc = item & 7;
        union { u16 u[8]; u32x4 v4; } pk;
#pragma unroll
        for (int q = 0; q < 8; ++q) pk.u[q] = f2h(tile[dc * 8 + q][tl]);
        *(u32x4*)(o16 + obase + (long)(t0 + tl) * D + d0 + dc * 8) = pk.v4;
    }
}

// fp32 [R][C] -> fp32 [C][R], z selects among 2 tensors (gamma/beta)
__global__ __launch_bounds__(256) void transpose_f32_2(const float* __restrict__ in0,
                                                       const float* __restrict__ in1,
                                                       float* __restrict__ out0,
                                                       float* __restrict__ out1,
                                                       int R, int C) {
    const float* in = blockIdx.z ? in1 : in0;
    float* out = blockIdx.z ? out1 : out0;
    __shared__ float tile[64][65];
    int c0 = blockIdx.x * 64, r0 = blockIdx.y * 64;
    int tx = threadIdx.x & 63, ty = threadIdx.x >> 6;
#pragma unroll
    for (int i = 0; i < 64; i += 4)
        tile[ty + i][tx] = in[(long)(r0 + ty + i) * C + c0 + tx];
    __syncthreads();
#pragma unroll
    for (int i = 0; i < 64; i += 4)
        out[(long)(c0 + ty + i) * R + r0 + tx] = tile[tx][ty + i];
}

// 4 equal-size fp32 -> fp16 conversions in one launch (z = which array)
__global__ __launch_bounds__(256) void conv_w4(const float* __restrict__ w0, u16* __restrict__ h0,
                                               const float* __restrict__ w1, u16* __restrict__ h1,
                                               const float* __restrict__ w2, u16* __restrict__ h2,
                                               const float* __restrict__ w3, u16* __restrict__ h3,
                                               int n) {
    int i = blockIdx.x * 256 + threadIdx.x;
    if (i >= n) return;
    const float* w; u16* h;
    switch (blockIdx.z) {
        case 0: w = w0; h = h0; break;
        case 1: w = w1; h = h1; break;
        case 2: w = w2; h = h2; break;
        default: w = w3; h = h3; break;
    }
    h[i] = f2h(w[i]);
}

// one block per score row (2048 cols), fp32 in (L3-resident), fp16 prob out
__global__ __launch_bounds__(256) void softmax_rows(const float* __restrict__ S, u16* __restrict__ P) {
    long row = (long)blockIdx.z * TT + blockIdx.x;
    const float* s = S + row * TT;
    u16* p = P + row * TT;
    int tid = threadIdx.x;
    f32x4 v0 = *(const f32x4*)(s + tid * 8);
    f32x4 v1 = *(const f32x4*)(s + tid * 8 + 4);
    float x[8] = {v0.x, v0.y, v0.z, v0.w, v1.x, v1.y, v1.z, v1.w};
    float m = x[0];
#pragma unroll
    for (int j = 1; j < 8; ++j) m = fmaxf(m, x[j]);
#pragma unroll
    for (int off = 32; off; off >>= 1) m = fmaxf(m, __shfl_xor(m, off, 64));
    __shared__ float red[8];
    int wave = tid >> 6, lane = tid & 63;
    if (lane == 0) red[wave] = m;
    __syncthreads();
    m = fmaxf(fmaxf(red[0], red[1]), fmaxf(red[2], red[3]));
    float e[8]; float sum = 0.f;
#pragma unroll
    for (int j = 0; j < 8; ++j) { e[j] = __expf(x[j] - m); sum += e[j]; }
#pragma unroll
    for (int off = 32; off; off >>= 1) sum += __shfl_xor(sum, off, 64);
    if (lane == 0) red[4 + wave] = sum;
    __syncthreads();
    sum = red[4] + red[5] + red[6] + red[7];
    float inv = 1.f / sum;
    union { u16 u[8]; u32x4 v4; } pk;
#pragma unroll
    for (int j = 0; j < 8; ++j) pk.u[j] = f2h(e[j] * inv);
    *(u32x4*)(p + tid * 8) = pk.v4;
}

__global__ void zero32(float* p) { p[threadIdx.x] = 0.f; }

__global__ __launch_bounds__(256) void ln_apply(const u16* __restrict__ TXp, const float* __restrict__ sums,
                                                const float* __restrict__ gT, const float* __restrict__ bT,
                                                u16* __restrict__ H) {
    int b = blockIdx.z;
    const float n = (float)(LL * TT);
    float mu = sums[b * 2] / n;
    float var = sums[b * 2 + 1] / n - mu * mu;
    float rstd = rsqrtf(var + LN_EPS);
    long base = (long)b * (LL * TT);
    long idx = ((long)blockIdx.x * 256 + threadIdx.x) * 8;
    u32x4 xv = *(const u32x4*)(TXp + base + idx);
    unsigned w[4] = {xv.x, xv.y, xv.z, xv.w};
    f32x4 g0 = *(const f32x4*)(gT + idx);
    f32x4 g1 = *(const f32x4*)(gT + idx + 4);
    f32x4 b0 = *(const f32x4*)(bT + idx);
    f32x4 b1 = *(const f32x4*)(bT + idx + 4);
    float g[8] = {g0.x, g0.y, g0.z, g0.w, g1.x, g1.y, g1.z, g1.w};
    float be[8] = {b0.x, b0.y, b0.z, b0.w, b1.x, b1.y, b1.z, b1.w};
    union { u16 u[8]; u32x4 v; } pk;
#pragma unroll
    for (int q = 0; q < 4; ++q) {
        float a = h2f((u16)(w[q] & 0xffff));
        float c = h2f((u16)(w[q] >> 16));
        float oa = fmaxf((a - mu) * rstd * g[q * 2] + be[q * 2], 0.f);
        float oc = fmaxf((c - mu) * rstd * g[q * 2 + 1] + be[q * 2 + 1], 0.f);
        pk.u[q * 2] = f2h(oa);
        pk.u[q * 2 + 1] = f2h(oc);
    }
    *(u32x4*)(H + base + idx) = pk.v;
}

extern "C" void kernel_launch(void* const* d_in, const int* in_sizes, int n_in,
                              void* d_out, int out_size, void* d_ws, size_t ws_size,
                              hipStream_t stream) {
    const float* input1  = (const float*)d_in[0];
    const float* input2  = (const float*)d_in[1];
    const float* theta_w = (const float*)d_in[2];
    const float* theta_b = (const float*)d_in[3];
    const float* phi_w   = (const float*)d_in[4];
    const float* phi_b   = (const float*)d_in[5];
    const float* g_w     = (const float*)d_in[6];
    const float* g_b     = (const float*)d_in[7];
    const float* ln_gamma= (const float*)d_in[8];
    const float* ln_beta = (const float*)d_in[9];
    const float* out_w   = (const float*)d_in[10];
    const float* out_b   = (const float*)d_in[11];
    float* out = (float*)d_out;

    char* ws = (char*)d_ws;
    const size_t MB = 1ull << 20;
    u16*  Xt     = (u16*)(ws + 0);          // 64MB [B][T][1024] fp16 (dead after projections)
    float* scores= (float*)(ws + 0);        // 64MB [4][T][T] fp32 (reuses Xt region, L3-resident)
    u16*  pmat   = (u16*)(ws + 64 * MB);    // 128MB [16][T][T] fp16
    u16*  Qf     = (u16*)(ws + 192 * MB);   // 32MB [B][T][L]
    u16*  Kf     = (u16*)(ws + 224 * MB);   // 32MB [B][T][L]
    u16*  Vt     = (u16*)(ws + 256 * MB);   // 32MB [B][L][T]
    u16*  TX     = (u16*)(ws + 288 * MB);   // 32MB [B][T][L] fp16
    u16*  H      = (u16*)(ws + 320 * MB);   // 32MB [B][T][L]
    u16*  thw    = (u16*)(ws + 352 * MB);   // 1MB each
    u16*  phw    = (u16*)(ws + 353 * MB);
    u16*  gww    = (u16*)(ws + 354 * MB);
    u16*  oww    = (u16*)(ws + 355 * MB);
    float* gammaT= (float*)(ws + 356 * MB); // 4MB [T][L]
    float* betaT = (float*)(ws + 360 * MB); // 4MB
    float* sums  = (float*)(ws + 364 * MB); // 128B

    dim3 blk(256), blkB(1024);

    conv_w4<<<dim3((LL * D2 + 255) / 256, 1, 4), blk, 0, stream>>>(
        theta_w, thw, phi_w, phw, g_w, gww, out_w, oww, LL * D2);
    transpose_f32_2<<<dim3(TT / 64, LL / 64, 2), blk, 0, stream>>>(
        ln_gamma, ln_beta, gammaT, betaT, LL, TT);
    zero32<<<dim3(1), dim3(32), 0, stream>>>(sums);

    // Q = theta(input2)
    transpose_h<<<dim3(TT / 64, D2 / 64, BB), blk, 0, stream>>>(input2, Xt, D2, TT);
    nt_gemm<2, 1, 0><<<dim3((LL / 256) * (TT / 256) * BB), blkB, 0, stream>>>(
        Xt, thw, (long)TT * D2, 0, (long)TT * LL, LL, D2, LL / 256, TT / 256,
        theta_b, Qf, nullptr, 0, nullptr);

    // K = phi(input1), V^T = g(input1)
    transpose_h<<<dim3(TT / 64, D1 / 64, BB), blk, 0, stream>>>(input1, Xt, D1, TT);
    nt_gemm<2, 1, 0><<<dim3((LL / 256) * (TT / 256) * BB), blkB, 0, stream>>>(
        Xt, phw, (long)TT * D1, 0, (long)TT * LL, LL, D1, LL / 256, TT / 256,
        phi_b, Kf, nullptr, 0, nullptr);
    nt_gemm<1, 1, 0><<<dim3((TT / 256) * (LL / 256) * BB), blkB, 0, stream>>>(
        gww, Xt, 0, (long)TT * D1, (long)LL * TT, TT, D1, TT / 256, LL / 256,
        g_b, Vt, nullptr, 0, nullptr);

    // attention scores+softmax, 4 batches per chunk (scores reuse Xt region)
    for (int c = 0; c < 4; ++c) {
        long qoff = (long)c * 4 * TT * LL;
        nt_gemm<0, 0, 0><<<dim3((TT / 256) * (TT / 256) * 4), blkB, 0, stream>>>(
            Qf + qoff, Kf + qoff, (long)TT * LL, (long)TT * LL, (long)TT * TT,
            TT, LL, TT / 256, TT / 256, nullptr, scores, nullptr, 0, nullptr);
        softmax_rows<<<dim3(TT, 1, 4), blk, 0, stream>>>(scores, pmat + (long)c * 4 * TT * TT);
    }
    // PV: one full-GPU dispatch over all 16 batches, LayerNorm sums fused
    nt_gemm<0, 1, 1><<<dim3((LL / 256) * (TT / 256) * BB), blkB, 0, stream>>>(
        pmat, Vt, (long)TT * TT, (long)LL * TT, (long)TT * LL,
        LL, TT, LL / 256, TT / 256, nullptr, TX, nullptr, 0, sums);

    ln_apply<<<dim3(512, 1, BB), blk, 0, stream>>>(TX, sums, gammaT, betaT, H);

    // out = out_w * h + out_b + input2  (small kernel, 4 blocks/CU — measured best)
    nt_gemm_sm<1, 3><<<dim3((TT / 128) * (D2 / 128) * BB), blk, 0, stream>>>(
        oww, H, 0, (long)TT * LL, (long)D2 * TT, TT, LL, TT / 128, D2 / 128,
        out_b, out, input2, (long)D2 * TT);
}